// Round 3
// baseline (901.478 us; speedup 1.0000x reference)
//
#include <hip/hip_runtime.h>

#define N_NODES 100000
#define N_EDGES 1600000
#define D_IN 128
#define D_HID 64
#define BN_EPS 1e-5f

#define BUCKET_SHIFT 7
#define BUCKET_W 128                                    // nodes per bucket
#define N_BUCKETS ((N_NODES + BUCKET_W - 1) / BUCKET_W) // 782
#define BCAP 4096                                       // fixed per-bucket capacity (mean 2046, sigma 45)
#define N_BIN_BLOCKS 256
#define EDGES_PER_BLOCK (N_EDGES / N_BIN_BLOCKS)        // 6250 exact
#define GT 2                                            // gemm tiles per block
#define ACC_STRIDE 65                                   // f32 row stride: (lc*65+8*ol+k)%32 -> exact 2-way

typedef __attribute__((ext_vector_type(8))) short bf16x8;
typedef __attribute__((ext_vector_type(4))) float f32x4;
typedef __attribute__((ext_vector_type(8))) _Float16 f16x8;

__device__ __forceinline__ ushort f2bf(float f) {       // RTNE fp32 -> bf16
    unsigned u = __float_as_uint(f);
    u += 0x7FFF + ((u >> 16) & 1);
    return (ushort)(u >> 16);
}

// --- 1. fused bin: LDS count -> reserve -> scatter; also global per-node degree ---
__global__ __launch_bounds__(256) void bin_scatter_kernel(const int* __restrict__ row,
                                                          const int* __restrict__ col,
                                                          int* __restrict__ deg,
                                                          int* __restrict__ bcursor,
                                                          int* __restrict__ binned) {
    __shared__ int hist[N_BUCKETS];
    __shared__ int lbase[N_BUCKETS];
    const int t = threadIdx.x;
    for (int i = t; i < N_BUCKETS; i += 256) hist[i] = 0;
    __syncthreads();
    const int e0 = blockIdx.x * EDGES_PER_BLOCK;
    for (int j = t; j < EDGES_PER_BLOCK; j += 256) {
        int c = col[e0 + j];
        atomicAdd(&hist[c >> BUCKET_SHIFT], 1);
        atomicAdd(&deg[c], 1);                           // global in-degree
    }
    __syncthreads();
    for (int i = t; i < N_BUCKETS; i += 256) {
        int h = hist[i];
        lbase[i] = h ? (i * BCAP + atomicAdd(&bcursor[i], h)) : 0;
        hist[i] = 0;   // local rank cursor
    }
    __syncthreads();
    for (int j = t; j < EDGES_PER_BLOCK; j += 256) {     // col re-read is L2-hot
        int c = col[e0 + j];
        int r = row[e0 + j];
        int b = c >> BUCKET_SHIFT;
        int rank = atomicAdd(&hist[b], 1);
        binned[lbase[b] + rank] = ((c & (BUCKET_W - 1)) << 17) | r;
    }
}

// --- 2. MFMA gemm: h_s(f16) = rsqrt(1+deg[n]) * (x @ W1) ---
__global__ __launch_bounds__(256) void gemm_mfma_kernel(const float* __restrict__ x,
                                                        const float* __restrict__ W,
                                                        const int* __restrict__ deg,
                                                        ushort* __restrict__ h_s) {
    __shared__ ushort xb[16 * 136];
    const int t = threadIdx.x;
    const int l = t & 63;
    const int wv = t >> 6;
    const int q = l >> 4;       // quad
    const int m = l & 15;
    bf16x8 bf[4];               // B[k=32s+8q+j][n=16wv+m]
    {
        const int n = wv * 16 + m;
        #pragma unroll
        for (int s = 0; s < 4; ++s)
            #pragma unroll
            for (int j = 0; j < 8; ++j)
                bf[s][j] = (short)f2bf(W[(32 * s + 8 * q + j) * D_HID + n]);
    }
    for (int tile = 0; tile < GT; ++tile) {
        const int node0 = blockIdx.x * (16 * GT) + tile * 16;
        __syncthreads();
        for (int i = t; i < 512; i += 256) {             // 16 rows x 32 float4
            int r = i >> 5, c4 = i & 31;
            float4 v = *(const float4*)&x[(size_t)(node0 + r) * D_IN + c4 * 4];
            ushort4 u = make_ushort4(f2bf(v.x), f2bf(v.y), f2bf(v.z), f2bf(v.w));
            *(ushort4*)&xb[r * 136 + c4 * 4] = u;
        }
        __syncthreads();
        f32x4 acc = {0.f, 0.f, 0.f, 0.f};
        #pragma unroll
        for (int s = 0; s < 4; ++s) {
            bf16x8 af = *(const bf16x8*)&xb[m * 136 + 32 * s + 8 * q];
            acc = __builtin_amdgcn_mfma_f32_16x16x32_bf16(af, bf[s], acc, 0, 0, 0);
        }
        #pragma unroll
        for (int r = 0; r < 4; ++r) {
            int node = node0 + q * 4 + r;    // C/D: row=(lane>>4)*4+reg, col=lane&15
            float dn = rsqrtf(1.0f + (float)deg[node]);
            _Float16 hv = (_Float16)(acc[r] * dn);
            h_s[node * D_HID + wv * 16 + m] = __builtin_bit_cast(unsigned short, hv);
        }
    }
}

// --- 3. fused bucket aggregate + BN/relu + fc (no counting sort) ---
// One block per bucket: float acc[128][65] in LDS; stream unsorted bucket edges,
// 8-lane octet per edge gathers one 128B h_s line, ds_add_f32 into LDS.
// Stride 65 => bank = (lc + 8*ol + k) % 32: 64 lanes cover each bank exactly 2x.
__global__ __launch_bounds__(512) void bucket_aggregate_kernel(const ushort* __restrict__ h_s,
                                                               const int* __restrict__ deg,
                                                               const int* __restrict__ bcursor,
                                                               const int* __restrict__ binned,
                                                               const float* __restrict__ b1,
                                                               const float* __restrict__ gamma,
                                                               const float* __restrict__ beta,
                                                               const float* __restrict__ mean,
                                                               const float* __restrict__ var,
                                                               const float* __restrict__ Wfc,
                                                               float4* __restrict__ uv) {
    __shared__ float acc[BUCKET_W * ACC_STRIDE];         // 8320 f32 = 33.3 KB
    const int b = blockIdx.x;
    const int t = threadIdx.x;
    {   // zero LDS (vectorized)
        float4 z = {0.f, 0.f, 0.f, 0.f};
        for (int i = t; i < (BUCKET_W * ACC_STRIDE) / 4; i += 512)
            ((float4*)acc)[i] = z;
    }
    __syncthreads();
    const f16x8* __restrict__ hsv = (const f16x8*)h_s;   // [node][8] octets
    const int s = b * BCAP;
    const int cnt = bcursor[b];
    const int og = t >> 3;                               // octet-group 0..63
    const int ol = t & 7;                                // feature octet 0..7
    int e = og;
    for (; e + 192 < cnt; e += 256) {                    // 4 gathers in flight/lane
        int p0 = binned[s + e];
        int p1 = binned[s + e + 64];
        int p2 = binned[s + e + 128];
        int p3 = binned[s + e + 192];
        f16x8 v0 = hsv[(p0 & 0x1FFFF) * 8 + ol];
        f16x8 v1 = hsv[(p1 & 0x1FFFF) * 8 + ol];
        f16x8 v2 = hsv[(p2 & 0x1FFFF) * 8 + ol];
        f16x8 v3 = hsv[(p3 & 0x1FFFF) * 8 + ol];
        int a0 = (p0 >> 17) * ACC_STRIDE + 8 * ol;
        int a1 = (p1 >> 17) * ACC_STRIDE + 8 * ol;
        int a2 = (p2 >> 17) * ACC_STRIDE + 8 * ol;
        int a3 = (p3 >> 17) * ACC_STRIDE + 8 * ol;
        #pragma unroll
        for (int k = 0; k < 8; ++k) atomicAdd(&acc[a0 + k], (float)v0[k]);
        #pragma unroll
        for (int k = 0; k < 8; ++k) atomicAdd(&acc[a1 + k], (float)v1[k]);
        #pragma unroll
        for (int k = 0; k < 8; ++k) atomicAdd(&acc[a2 + k], (float)v2[k]);
        #pragma unroll
        for (int k = 0; k < 8; ++k) atomicAdd(&acc[a3 + k], (float)v3[k]);
    }
    for (; e < cnt; e += 64) {
        int p = binned[s + e];
        f16x8 v = hsv[(p & 0x1FFFF) * 8 + ol];
        int a = (p >> 17) * ACC_STRIDE + 8 * ol;
        #pragma unroll
        for (int k = 0; k < 8; ++k) atomicAdd(&acc[a + k], (float)v[k]);
    }
    __syncthreads();
    // epilogue: 4 threads per node, 16 feats each
    const int n_loc = t >> 2;                            // 0..127
    const int node = b * BUCKET_W + n_loc;
    const int f0 = (t & 3) * 16;
    if (node < N_NODES) {
        const float dn = rsqrtf(1.0f + (float)deg[node]);
        float p0 = 0.f, p1 = 0.f, p2 = 0.f, p3 = 0.f;
        #pragma unroll
        for (int qc = 0; qc < 2; ++qc) {                 // two f16x8 self chunks
            f16x8 sv = hsv[node * 8 + (f0 >> 3) + qc];
            #pragma unroll
            for (int h = 0; h < 2; ++h) {                // 4-feat halves
                const int f = f0 + 8 * qc + 4 * h;
                float4 bb = *(const float4*)&b1[f];
                float4 mu = *(const float4*)&mean[f];
                float4 vr = *(const float4*)&var[f];
                float4 gm = *(const float4*)&gamma[f];
                float4 bt = *(const float4*)&beta[f];
                float4 wA = *(const float4*)&Wfc[2 * f];        // rows f, f+1
                float4 wB = *(const float4*)&Wfc[2 * f + 4];    // rows f+2, f+3
                float4 wC = *(const float4*)&Wfc[128 + 2 * f];
                float4 wD = *(const float4*)&Wfc[128 + 2 * f + 4];
                float a0 = (acc[n_loc * ACC_STRIDE + f + 0] + (float)sv[4 * h + 0]) * dn;
                float a1 = (acc[n_loc * ACC_STRIDE + f + 1] + (float)sv[4 * h + 1]) * dn;
                float a2 = (acc[n_loc * ACC_STRIDE + f + 2] + (float)sv[4 * h + 2]) * dn;
                float a3 = (acc[n_loc * ACC_STRIDE + f + 3] + (float)sv[4 * h + 3]) * dn;
                a0 = fmaxf(a0 + bb.x, 0.f);
                a1 = fmaxf(a1 + bb.y, 0.f);
                a2 = fmaxf(a2 + bb.z, 0.f);
                a3 = fmaxf(a3 + bb.w, 0.f);
                a0 = fmaxf((a0 - mu.x) * rsqrtf(vr.x + BN_EPS) * gm.x + bt.x, 0.f);
                a1 = fmaxf((a1 - mu.y) * rsqrtf(vr.y + BN_EPS) * gm.y + bt.y, 0.f);
                a2 = fmaxf((a2 - mu.z) * rsqrtf(vr.z + BN_EPS) * gm.z + bt.z, 0.f);
                a3 = fmaxf((a3 - mu.w) * rsqrtf(vr.w + BN_EPS) * gm.w + bt.w, 0.f);
                p0 += a0 * wA.x + a1 * wA.z + a2 * wB.x + a3 * wB.z;
                p1 += a0 * wA.y + a1 * wA.w + a2 * wB.y + a3 * wB.w;
                p2 += a0 * wC.x + a1 * wC.z + a2 * wD.x + a3 * wD.z;
                p3 += a0 * wC.y + a1 * wC.w + a2 * wD.y + a3 * wD.w;
            }
        }
        p0 += __shfl_xor(p0, 1, 64); p0 += __shfl_xor(p0, 2, 64);
        p1 += __shfl_xor(p1, 1, 64); p1 += __shfl_xor(p1, 2, 64);
        p2 += __shfl_xor(p2, 1, 64); p2 += __shfl_xor(p2, 2, 64);
        p3 += __shfl_xor(p3, 1, 64); p3 += __shfl_xor(p3, 2, 64);
        if ((t & 3) == 0) uv[node] = make_float4(p0, p1, p2, p3);
    }
}

// --- 4. edge head: 2 edges/thread; out = uv[row].xy + uv[col].zw + bfc ---
__global__ __launch_bounds__(256) void edgeout_kernel(const int* __restrict__ row,
                                                      const int* __restrict__ col,
                                                      const float4* __restrict__ uv,
                                                      const float* __restrict__ bfc,
                                                      float2* __restrict__ out) {
    int i = blockIdx.x * 256 + threadIdx.x;          // over N_EDGES/2 (grid exact)
    int e = i * 2;
    int2 rr = *(const int2*)&row[e];
    int2 cc = *(const int2*)&col[e];
    float4 a0 = uv[rr.x];
    float4 b0 = uv[cc.x];
    float4 a1 = uv[rr.y];
    float4 b1 = uv[cc.y];
    float c0 = bfc[0], c1 = bfc[1];
    float4 o = make_float4(a0.x + b0.z + c0, a0.y + b0.w + c1,
                           a1.x + b1.z + c0, a1.y + b1.w + c1);
    *(float4*)&out[e] = o;
}

extern "C" void kernel_launch(void* const* d_in, const int* in_sizes, int n_in,
                              void* d_out, int out_size, void* d_ws, size_t ws_size,
                              hipStream_t stream) {
    const float* x     = (const float*)d_in[0];
    const int*   ei    = (const int*)d_in[1];
    const int*   row   = ei;             // sources
    const int*   col   = ei + N_EDGES;   // targets
    const float* W1    = (const float*)d_in[2];
    const float* b1    = (const float*)d_in[3];
    const float* gamma = (const float*)d_in[4];
    const float* beta  = (const float*)d_in[5];
    const float* mean  = (const float*)d_in[6];
    const float* var   = (const float*)d_in[7];
    const float* Wfc   = (const float*)d_in[8];
    const float* bfc   = (const float*)d_in[9];
    float2* out = (float2*)d_out;

    char* ws = (char*)d_ws;
    size_t off = 0;
    ushort* h_s      = (ushort*)(ws + off); off += (size_t)N_NODES * D_HID * 2;    // 12.8 MB
    int*   binned    = (int*)(ws + off);    off += (size_t)N_BUCKETS * BCAP * 4;   // 12.8 MB
    int*   deg       = (int*)(ws + off);    off += (size_t)N_NODES * 4;            // 0.4 MB
    int*   bcursor   = (int*)(ws + off);    off += ((size_t)N_BUCKETS * 4 + 15) & ~(size_t)15;
    float4* uv       = (float4*)(ws + off); off += (size_t)N_NODES * 16;           // 1.6 MB

    // deg and bcursor are adjacent: one memset covers both
    hipMemsetAsync(deg, 0, (size_t)(N_NODES + N_BUCKETS) * sizeof(int) + 16, stream);
    bin_scatter_kernel<<<N_BIN_BLOCKS, 256, 0, stream>>>(row, col, deg, bcursor, binned);
    gemm_mfma_kernel<<<N_NODES / (16 * GT), 256, 0, stream>>>(x, W1, deg, h_s);
    bucket_aggregate_kernel<<<N_BUCKETS, 512, 0, stream>>>(h_s, deg, bcursor, binned,
                                                           b1, gamma, beta, mean, var,
                                                           Wfc, uv);
    edgeout_kernel<<<N_EDGES / 512, 256, 0, stream>>>(row, col, uv, bfc, out);
}

// Round 5
// 251.788 us; speedup vs baseline: 3.5803x; 3.5803x over previous
//
#include <hip/hip_runtime.h>

#define N_NODES 100000
#define N_EDGES 1600000
#define D_IN 128
#define D_HID 64
#define BN_EPS 1e-5f

#define BUCKET_SHIFT 7
#define BUCKET_W 128                                    // nodes per bucket
#define N_BUCKETS ((N_NODES + BUCKET_W - 1) / BUCKET_W) // 782
#define BCAP 4096                                       // per-bucket region (mean 2046, sigma 45)
#define ECAP 2560                                       // LDS edge staging (mean+11sigma)
#define N_BIN_BLOCKS 256
#define EDGES_PER_BLOCK (N_EDGES / N_BIN_BLOCKS)        // 6250 exact
#define GT 2                                            // gemm tiles per block

typedef __attribute__((ext_vector_type(8))) short bf16x8;
typedef __attribute__((ext_vector_type(4))) float f32x4;
typedef __attribute__((ext_vector_type(8))) _Float16 f16x8;

__device__ __forceinline__ ushort f2bf(float f) {       // RTNE fp32 -> bf16
    unsigned u = __float_as_uint(f);
    u += 0x7FFF + ((u >> 16) & 1);
    return (ushort)(u >> 16);
}

// --- 1. fused bin: LDS count -> reserve -> scatter; also global per-node degree ---
__global__ __launch_bounds__(256) void bin_scatter_kernel(const int* __restrict__ row,
                                                          const int* __restrict__ col,
                                                          int* __restrict__ deg,
                                                          int* __restrict__ bcursor,
                                                          int* __restrict__ binned) {
    __shared__ int hist[N_BUCKETS];
    __shared__ int lbase[N_BUCKETS];
    const int t = threadIdx.x;
    for (int i = t; i < N_BUCKETS; i += 256) hist[i] = 0;
    __syncthreads();
    const int e0 = blockIdx.x * EDGES_PER_BLOCK;
    for (int j = t; j < EDGES_PER_BLOCK; j += 256) {
        int c = col[e0 + j];
        atomicAdd(&hist[c >> BUCKET_SHIFT], 1);
        atomicAdd(&deg[c], 1);                           // global in-degree
    }
    __syncthreads();
    for (int i = t; i < N_BUCKETS; i += 256) {
        int h = hist[i];
        lbase[i] = h ? (i * BCAP + atomicAdd(&bcursor[i], h)) : 0;
        hist[i] = 0;   // local rank cursor
    }
    __syncthreads();
    for (int j = t; j < EDGES_PER_BLOCK; j += 256) {     // col re-read is L2-hot
        int c = col[e0 + j];
        int r = row[e0 + j];
        int b = c >> BUCKET_SHIFT;
        int rank = atomicAdd(&hist[b], 1);
        binned[lbase[b] + rank] = ((c & (BUCKET_W - 1)) << 17) | r;
    }
}

// --- 2. MFMA gemm: h_s(f16) = rsqrt(1+deg[n]) * (x @ W1) ---
__global__ __launch_bounds__(256) void gemm_mfma_kernel(const float* __restrict__ x,
                                                        const float* __restrict__ W,
                                                        const int* __restrict__ deg,
                                                        ushort* __restrict__ h_s) {
    __shared__ ushort xb[16 * 136];
    const int t = threadIdx.x;
    const int l = t & 63;
    const int wv = t >> 6;
    const int q = l >> 4;       // quad
    const int m = l & 15;
    bf16x8 bf[4];               // B[k=32s+8q+j][n=16wv+m]
    {
        const int n = wv * 16 + m;
        #pragma unroll
        for (int s = 0; s < 4; ++s)
            #pragma unroll
            for (int j = 0; j < 8; ++j)
                bf[s][j] = (short)f2bf(W[(32 * s + 8 * q + j) * D_HID + n]);
    }
    for (int tile = 0; tile < GT; ++tile) {
        const int node0 = blockIdx.x * (16 * GT) + tile * 16;
        __syncthreads();
        for (int i = t; i < 512; i += 256) {             // 16 rows x 32 float4
            int r = i >> 5, c4 = i & 31;
            float4 v = *(const float4*)&x[(size_t)(node0 + r) * D_IN + c4 * 4];
            ushort4 u = make_ushort4(f2bf(v.x), f2bf(v.y), f2bf(v.z), f2bf(v.w));
            *(ushort4*)&xb[r * 136 + c4 * 4] = u;
        }
        __syncthreads();
        f32x4 acc = {0.f, 0.f, 0.f, 0.f};
        #pragma unroll
        for (int s = 0; s < 4; ++s) {
            bf16x8 af = *(const bf16x8*)&xb[m * 136 + 32 * s + 8 * q];
            acc = __builtin_amdgcn_mfma_f32_16x16x32_bf16(af, bf[s], acc, 0, 0, 0);
        }
        #pragma unroll
        for (int r = 0; r < 4; ++r) {
            int node = node0 + q * 4 + r;    // C/D: row=(lane>>4)*4+reg, col=lane&15
            float dn = rsqrtf(1.0f + (float)deg[node]);
            _Float16 hv = (_Float16)(acc[r] * dn);
            h_s[node * D_HID + wv * 16 + m] = __builtin_bit_cast(unsigned short, hv);
        }
    }
}

// --- 3. fused sort + aggregate + bias/BN/relu + fc ---
// One block per bucket: stage packed edges in LDS, counting-sort to a
// per-node LDS list (int atomics only, same as old bucket_csr), then the
// verified R2 aggregate: 8-lane octet per node, f16x8 (16B) gathers, plain
// VGPR adds. Kills the bucket_csr dispatch and its 12.8MB global round-trip.
__global__ __launch_bounds__(512) void aggregate_kernel(const ushort* __restrict__ h_s,
                                                        const int* __restrict__ bcursor,
                                                        const int* __restrict__ binned,
                                                        const float* __restrict__ b1,
                                                        const float* __restrict__ gamma,
                                                        const float* __restrict__ beta,
                                                        const float* __restrict__ mean,
                                                        const float* __restrict__ var,
                                                        const float* __restrict__ Wfc,
                                                        float4* __restrict__ uv) {
    __shared__ int eb[ECAP];        // staged packed edges
    __shared__ int csr[ECAP];       // sorted local src ids
    __shared__ int hist[BUCKET_W];  // per-node count (persists = in-degree)
    __shared__ int cursor[BUCKET_W];
    __shared__ int startsh[BUCKET_W];
    const int b = blockIdx.x;
    const int t = threadIdx.x;
    if (t < BUCKET_W) hist[t] = 0;
    __syncthreads();
    const int s = b * BCAP;
    const int cnt = bcursor[b];
    for (int i = t; i < cnt; i += 512) {                 // stage + histogram
        int p = binned[s + i];
        eb[i] = p;
        atomicAdd(&hist[p >> 17], 1);
    }
    __syncthreads();
    if (t < BUCKET_W) cursor[t] = hist[t];
    for (int off = 1; off < BUCKET_W; off <<= 1) {       // inclusive scan
        __syncthreads();
        int add = (t >= off && t < BUCKET_W) ? cursor[t - off] : 0;
        __syncthreads();
        if (t < BUCKET_W) cursor[t] += add;
    }
    __syncthreads();
    if (t < BUCKET_W) {
        int excl = cursor[t] - hist[t];
        startsh[t] = excl;
        cursor[t] = excl;
    }
    __syncthreads();
    for (int i = t; i < cnt; i += 512) {                 // scatter to sorted list
        int p = eb[i];
        int pos = atomicAdd(&cursor[p >> 17], 1);
        csr[pos] = p & 0x1FFFF;
    }
    __syncthreads();
    // aggregate: octet (8 lanes) per node; 64 octets -> 2 rounds of 128 nodes
    const f16x8* __restrict__ hsv = (const f16x8*)h_s;   // [node][8] octets
    const int ol = t & 7;                                // feature octet 0..7
    #pragma unroll
    for (int r = 0; r < 2; ++r) {
        const int nl = (t >> 3) + r * 64;                // local node 0..127
        const int node = b * BUCKET_W + nl;
        f16x8 acc = hsv[node * 8 + ol];                  // self-loop (pre-scaled)
        const int st = startsh[nl];
        const int cn = hist[nl];
        int j = 0;
        for (; j + 8 <= cn; j += 8) {                    // 8 gathers in flight/octet
            int i0 = csr[st + j + 0];
            int i1 = csr[st + j + 1];
            int i2 = csr[st + j + 2];
            int i3 = csr[st + j + 3];
            int i4 = csr[st + j + 4];
            int i5 = csr[st + j + 5];
            int i6 = csr[st + j + 6];
            int i7 = csr[st + j + 7];
            f16x8 v0 = hsv[i0 * 8 + ol];
            f16x8 v1 = hsv[i1 * 8 + ol];
            f16x8 v2 = hsv[i2 * 8 + ol];
            f16x8 v3 = hsv[i3 * 8 + ol];
            f16x8 v4 = hsv[i4 * 8 + ol];
            f16x8 v5 = hsv[i5 * 8 + ol];
            f16x8 v6 = hsv[i6 * 8 + ol];
            f16x8 v7 = hsv[i7 * 8 + ol];
            acc += v0; acc += v1; acc += v2; acc += v3;
            acc += v4; acc += v5; acc += v6; acc += v7;
        }
        for (; j + 4 <= cn; j += 4) {
            int i0 = csr[st + j + 0];
            int i1 = csr[st + j + 1];
            int i2 = csr[st + j + 2];
            int i3 = csr[st + j + 3];
            f16x8 v0 = hsv[i0 * 8 + ol];
            f16x8 v1 = hsv[i1 * 8 + ol];
            f16x8 v2 = hsv[i2 * 8 + ol];
            f16x8 v3 = hsv[i3 * 8 + ol];
            acc += v0; acc += v1; acc += v2; acc += v3;
        }
        for (; j + 2 <= cn; j += 2) {
            int i0 = csr[st + j + 0];
            int i1 = csr[st + j + 1];
            f16x8 v0 = hsv[i0 * 8 + ol];
            f16x8 v1 = hsv[i1 * 8 + ol];
            acc += v0; acc += v1;
        }
        if (j < cn)
            acc += hsv[csr[st + j] * 8 + ol];
        // epilogue: lane handles features f0..f0+7 of node
        const float dn = rsqrtf(1.0f + (float)cn);
        const int f0 = 8 * ol;
        float a[8];
        #pragma unroll
        for (int k = 0; k < 8; ++k) a[k] = (float)acc[k] * dn;
        float bb[8], mu[8], vr[8], gm[8], bt[8];
        *(float4*)&bb[0] = *(const float4*)&b1[f0];    *(float4*)&bb[4] = *(const float4*)&b1[f0 + 4];
        *(float4*)&mu[0] = *(const float4*)&mean[f0];  *(float4*)&mu[4] = *(const float4*)&mean[f0 + 4];
        *(float4*)&vr[0] = *(const float4*)&var[f0];   *(float4*)&vr[4] = *(const float4*)&var[f0 + 4];
        *(float4*)&gm[0] = *(const float4*)&gamma[f0]; *(float4*)&gm[4] = *(const float4*)&gamma[f0 + 4];
        *(float4*)&bt[0] = *(const float4*)&beta[f0];  *(float4*)&bt[4] = *(const float4*)&beta[f0 + 4];
        #pragma unroll
        for (int k = 0; k < 8; ++k) {
            float v = fmaxf(a[k] + bb[k], 0.f);
            a[k] = fmaxf((v - mu[k]) * rsqrtf(vr[k] + BN_EPS) * gm[k] + bt[k], 0.f);
        }
        float wt[16], wb[16];
        #pragma unroll
        for (int k = 0; k < 4; ++k) {
            *(float4*)&wt[4 * k] = *(const float4*)&Wfc[2 * f0 + 4 * k];
            *(float4*)&wb[4 * k] = *(const float4*)&Wfc[128 + 2 * f0 + 4 * k];
        }
        float p0 = 0.f, p1 = 0.f, p2 = 0.f, p3 = 0.f;
        #pragma unroll
        for (int k = 0; k < 8; ++k) {
            p0 += a[k] * wt[2 * k];
            p1 += a[k] * wt[2 * k + 1];
            p2 += a[k] * wb[2 * k];
            p3 += a[k] * wb[2 * k + 1];
        }
        #pragma unroll
        for (int off = 4; off > 0; off >>= 1) {          // reduce within octet
            p0 += __shfl_xor(p0, off, 64);
            p1 += __shfl_xor(p1, off, 64);
            p2 += __shfl_xor(p2, off, 64);
            p3 += __shfl_xor(p3, off, 64);
        }
        if (ol == 0 && node < N_NODES) uv[node] = make_float4(p0, p1, p2, p3);
    }
}

// --- 4. edge head: 2 edges/thread; out = uv[row].xy + uv[col].zw + bfc ---
__global__ __launch_bounds__(256) void edgeout_kernel(const int* __restrict__ row,
                                                      const int* __restrict__ col,
                                                      const float4* __restrict__ uv,
                                                      const float* __restrict__ bfc,
                                                      float2* __restrict__ out) {
    int i = blockIdx.x * 256 + threadIdx.x;          // over N_EDGES/2 (grid exact)
    int e = i * 2;
    int2 rr = *(const int2*)&row[e];
    int2 cc = *(const int2*)&col[e];
    float4 a0 = uv[rr.x];
    float4 b0 = uv[cc.x];
    float4 a1 = uv[rr.y];
    float4 b1 = uv[cc.y];
    float c0 = bfc[0], c1 = bfc[1];
    float4 o = make_float4(a0.x + b0.z + c0, a0.y + b0.w + c1,
                           a1.x + b1.z + c0, a1.y + b1.w + c1);
    *(float4*)&out[e] = o;
}

extern "C" void kernel_launch(void* const* d_in, const int* in_sizes, int n_in,
                              void* d_out, int out_size, void* d_ws, size_t ws_size,
                              hipStream_t stream) {
    const float* x     = (const float*)d_in[0];
    const int*   ei    = (const int*)d_in[1];
    const int*   row   = ei;             // sources
    const int*   col   = ei + N_EDGES;   // targets
    const float* W1    = (const float*)d_in[2];
    const float* b1    = (const float*)d_in[3];
    const float* gamma = (const float*)d_in[4];
    const float* beta  = (const float*)d_in[5];
    const float* mean  = (const float*)d_in[6];
    const float* var   = (const float*)d_in[7];
    const float* Wfc   = (const float*)d_in[8];
    const float* bfc   = (const float*)d_in[9];
    float2* out = (float2*)d_out;

    char* ws = (char*)d_ws;
    size_t off = 0;
    ushort* h_s      = (ushort*)(ws + off); off += (size_t)N_NODES * D_HID * 2;    // 12.8 MB
    int*   binned    = (int*)(ws + off);    off += (size_t)N_BUCKETS * BCAP * 4;   // 12.8 MB
    int*   deg       = (int*)(ws + off);    off += (size_t)N_NODES * 4;            // 0.4 MB
    int*   bcursor   = (int*)(ws + off);    off += ((size_t)N_BUCKETS * 4 + 15) & ~(size_t)15;
    float4* uv       = (float4*)(ws + off); off += (size_t)N_NODES * 16;           // 1.6 MB

    // deg and bcursor are adjacent: one memset covers both
    hipMemsetAsync(deg, 0, (size_t)(N_NODES + N_BUCKETS) * sizeof(int) + 16, stream);
    bin_scatter_kernel<<<N_BIN_BLOCKS, 256, 0, stream>>>(row, col, deg, bcursor, binned);
    gemm_mfma_kernel<<<N_NODES / (16 * GT), 256, 0, stream>>>(x, W1, deg, h_s);
    aggregate_kernel<<<N_BUCKETS, 512, 0, stream>>>(h_s, bcursor, binned,
                                                    b1, gamma, beta, mean, var,
                                                    Wfc, uv);
    edgeout_kernel<<<N_EDGES / 512, 256, 0, stream>>>(row, col, uv, bfc, out);
}

// Round 6
// 197.932 us; speedup vs baseline: 4.5545x; 1.2721x over previous
//
#include <hip/hip_runtime.h>

#define N_NODES 100000
#define N_EDGES 1600000
#define D_IN 128
#define D_HID 64
#define BN_EPS 1e-5f

#define BUCKET_SHIFT 7
#define BUCKET_W 128                                    // nodes per bucket
#define N_BUCKETS ((N_NODES + BUCKET_W - 1) / BUCKET_W) // 782
#define BCAP 4096                                       // fixed per-bucket capacity (mean 2046, sigma 45)
#define N_BIN_BLOCKS 256
#define EDGES_PER_BLOCK (N_EDGES / N_BIN_BLOCKS)        // 6250 exact
#define GT 2                                            // gemm tiles per block

typedef __attribute__((ext_vector_type(8))) short bf16x8;
typedef __attribute__((ext_vector_type(4))) float f32x4;
typedef __attribute__((ext_vector_type(8))) _Float16 f16x8;

__device__ __forceinline__ ushort f2bf(float f) {       // RTNE fp32 -> bf16
    unsigned u = __float_as_uint(f);
    u += 0x7FFF + ((u >> 16) & 1);
    return (ushort)(u >> 16);
}

// --- 1. fused bin: LDS count -> reserve -> scatter ---
// 1024 threads: 16 waves/CU (grid is 1 block/CU) to hide LDS-atomic +
// scattered-store latency; R5 showed 4 waves/CU left the CU 99% idle.
__global__ __launch_bounds__(1024) void bin_scatter_kernel(const int* __restrict__ row,
                                                           const int* __restrict__ col,
                                                           int* __restrict__ bcursor,
                                                           int* __restrict__ binned) {
    __shared__ int hist[N_BUCKETS];
    __shared__ int lbase[N_BUCKETS];
    const int t = threadIdx.x;
    for (int i = t; i < N_BUCKETS; i += 1024) hist[i] = 0;
    __syncthreads();
    const int e0 = blockIdx.x * EDGES_PER_BLOCK;
    for (int j = t; j < EDGES_PER_BLOCK; j += 1024)
        atomicAdd(&hist[col[e0 + j] >> BUCKET_SHIFT], 1);
    __syncthreads();
    for (int i = t; i < N_BUCKETS; i += 1024) {
        int h = hist[i];
        lbase[i] = h ? (i * BCAP + atomicAdd(&bcursor[i], h)) : 0;
        hist[i] = 0;   // local rank cursor
    }
    __syncthreads();
    for (int j = t; j < EDGES_PER_BLOCK; j += 1024) {    // col re-read is L2-hot
        int c = col[e0 + j];
        int r = row[e0 + j];
        int b = c >> BUCKET_SHIFT;
        int rank = atomicAdd(&hist[b], 1);
        binned[lbase[b] + rank] = ((c & (BUCKET_W - 1)) << 17) | r;
    }
}

// --- 2. bucket-local counting sort -> CSR + (start,cnt) + dinv ---
// 512 threads: 24 waves/CU for the histogram/scatter passes.
__global__ __launch_bounds__(512) void bucket_csr_kernel(const int* __restrict__ binned,
                                                         const int* __restrict__ bcursor,
                                                         int* __restrict__ csr_src,
                                                         int2* __restrict__ rs2,
                                                         float* __restrict__ dinv) {
    __shared__ int hist[BUCKET_W];
    __shared__ int cursor[BUCKET_W];
    const int b = blockIdx.x;
    const int t = threadIdx.x;
    if (t < BUCKET_W) hist[t] = 0;
    __syncthreads();
    const int s = b * BCAP;
    const int e = s + bcursor[b];
    for (int i = s + t; i < e; i += 512)
        atomicAdd(&hist[binned[i] >> 17], 1);
    __syncthreads();
    if (t < BUCKET_W) cursor[t] = hist[t];
    for (int off = 1; off < BUCKET_W; off <<= 1) {
        __syncthreads();
        int add = (t >= off && t < BUCKET_W) ? cursor[t - off] : 0;
        __syncthreads();
        if (t < BUCKET_W) cursor[t] += add;
    }
    __syncthreads();
    int excl = (t < BUCKET_W) ? (cursor[t] - hist[t]) : 0;
    __syncthreads();
    if (t < BUCKET_W) cursor[t] = excl;
    const int node = b * BUCKET_W + t;
    if (t < BUCKET_W && node < N_NODES) {
        rs2[node] = make_int2(s + excl, hist[t]);
        dinv[node] = rsqrtf(1.0f + (float)hist[t]);
    }
    __syncthreads();
    for (int i = s + t; i < e; i += 512) {
        int p = binned[i];
        int pos = atomicAdd(&cursor[p >> 17], 1);
        csr_src[s + pos] = p & 0x1FFFF;
    }
}

// --- 3. MFMA gemm: h_s(f16) = dinv[n] * (x @ W1) ---
__global__ __launch_bounds__(256) void gemm_mfma_kernel(const float* __restrict__ x,
                                                        const float* __restrict__ W,
                                                        const float* __restrict__ dinv,
                                                        ushort* __restrict__ h_s) {
    __shared__ ushort xb[16 * 136];
    const int t = threadIdx.x;
    const int l = t & 63;
    const int wv = t >> 6;
    const int q = l >> 4;       // quad
    const int m = l & 15;
    bf16x8 bf[4];               // B[k=32s+8q+j][n=16wv+m]
    {
        const int n = wv * 16 + m;
        #pragma unroll
        for (int s = 0; s < 4; ++s)
            #pragma unroll
            for (int j = 0; j < 8; ++j)
                bf[s][j] = (short)f2bf(W[(32 * s + 8 * q + j) * D_HID + n]);
    }
    for (int tile = 0; tile < GT; ++tile) {
        const int node0 = blockIdx.x * (16 * GT) + tile * 16;
        __syncthreads();
        for (int i = t; i < 512; i += 256) {             // 16 rows x 32 float4
            int r = i >> 5, c4 = i & 31;
            float4 v = *(const float4*)&x[(size_t)(node0 + r) * D_IN + c4 * 4];
            ushort4 u = make_ushort4(f2bf(v.x), f2bf(v.y), f2bf(v.z), f2bf(v.w));
            *(ushort4*)&xb[r * 136 + c4 * 4] = u;
        }
        __syncthreads();
        f32x4 acc = {0.f, 0.f, 0.f, 0.f};
        #pragma unroll
        for (int s = 0; s < 4; ++s) {
            bf16x8 af = *(const bf16x8*)&xb[m * 136 + 32 * s + 8 * q];
            acc = __builtin_amdgcn_mfma_f32_16x16x32_bf16(af, bf[s], acc, 0, 0, 0);
        }
        #pragma unroll
        for (int r = 0; r < 4; ++r) {
            int node = node0 + q * 4 + r;    // C/D: row=(lane>>4)*4+reg, col=lane&15
            _Float16 hv = (_Float16)(acc[r] * dinv[node]);
            h_s[node * D_HID + wv * 16 + m] = __builtin_bit_cast(unsigned short, hv);
        }
    }
}

// --- 4. fused aggregate + bias/BN/relu + fc projection ---
// 8 nodes per wave: one 8-lane octet per node, f16x8 (16B) per lane =
// one full 128B node line per gather group. (Verified R2 structure.)
__global__ __launch_bounds__(256) void aggregate_kernel(const ushort* __restrict__ h_s,
                                                        const float* __restrict__ dinv,
                                                        const int2* __restrict__ rs2,
                                                        const int* __restrict__ csr_src,
                                                        const float* __restrict__ b1,
                                                        const float* __restrict__ gamma,
                                                        const float* __restrict__ beta,
                                                        const float* __restrict__ mean,
                                                        const float* __restrict__ var,
                                                        const float* __restrict__ Wfc,
                                                        float4* __restrict__ uv) {
    const f16x8* __restrict__ hsv = (const f16x8*)h_s;   // [node][8] octets
    const int wvid = (blockIdx.x * 256 + threadIdx.x) >> 6; // wave id (grid exact)
    const int lane = threadIdx.x & 63;
    const int oct = lane >> 3;                           // node slot 0..7
    const int ol = lane & 7;                             // feature octet 0..7
    const int n = wvid * 8 + oct;                        // node
    f16x8 acc = hsv[n * 8 + ol];                         // self-loop (pre-scaled)
    const int2 rs = rs2[n];
    const int start = rs.x;
    const int cnt = rs.y;
    int j = 0;
    for (; j + 8 <= cnt; j += 8) {                       // 8 gathers in flight/octet
        int i0 = csr_src[start + j + 0];
        int i1 = csr_src[start + j + 1];
        int i2 = csr_src[start + j + 2];
        int i3 = csr_src[start + j + 3];
        int i4 = csr_src[start + j + 4];
        int i5 = csr_src[start + j + 5];
        int i6 = csr_src[start + j + 6];
        int i7 = csr_src[start + j + 7];
        f16x8 v0 = hsv[i0 * 8 + ol];
        f16x8 v1 = hsv[i1 * 8 + ol];
        f16x8 v2 = hsv[i2 * 8 + ol];
        f16x8 v3 = hsv[i3 * 8 + ol];
        f16x8 v4 = hsv[i4 * 8 + ol];
        f16x8 v5 = hsv[i5 * 8 + ol];
        f16x8 v6 = hsv[i6 * 8 + ol];
        f16x8 v7 = hsv[i7 * 8 + ol];
        acc += v0; acc += v1; acc += v2; acc += v3;
        acc += v4; acc += v5; acc += v6; acc += v7;
    }
    for (; j + 4 <= cnt; j += 4) {
        int i0 = csr_src[start + j + 0];
        int i1 = csr_src[start + j + 1];
        int i2 = csr_src[start + j + 2];
        int i3 = csr_src[start + j + 3];
        f16x8 v0 = hsv[i0 * 8 + ol];
        f16x8 v1 = hsv[i1 * 8 + ol];
        f16x8 v2 = hsv[i2 * 8 + ol];
        f16x8 v3 = hsv[i3 * 8 + ol];
        acc += v0; acc += v1; acc += v2; acc += v3;
    }
    for (; j + 2 <= cnt; j += 2) {
        int i0 = csr_src[start + j + 0];
        int i1 = csr_src[start + j + 1];
        f16x8 v0 = hsv[i0 * 8 + ol];
        f16x8 v1 = hsv[i1 * 8 + ol];
        acc += v0; acc += v1;
    }
    if (j < cnt)
        acc += hsv[csr_src[start + j] * 8 + ol];
    // epilogue: lane handles features f0..f0+7 of node n
    const float dn = dinv[n];
    const int f0 = 8 * ol;
    float a[8];
    #pragma unroll
    for (int k = 0; k < 8; ++k) a[k] = (float)acc[k] * dn;
    float bb[8], mu[8], vr[8], gm[8], bt[8];
    *(float4*)&bb[0] = *(const float4*)&b1[f0];    *(float4*)&bb[4] = *(const float4*)&b1[f0 + 4];
    *(float4*)&mu[0] = *(const float4*)&mean[f0];  *(float4*)&mu[4] = *(const float4*)&mean[f0 + 4];
    *(float4*)&vr[0] = *(const float4*)&var[f0];   *(float4*)&vr[4] = *(const float4*)&var[f0 + 4];
    *(float4*)&gm[0] = *(const float4*)&gamma[f0]; *(float4*)&gm[4] = *(const float4*)&gamma[f0 + 4];
    *(float4*)&bt[0] = *(const float4*)&beta[f0];  *(float4*)&bt[4] = *(const float4*)&beta[f0 + 4];
    #pragma unroll
    for (int k = 0; k < 8; ++k) {
        float v = fmaxf(a[k] + bb[k], 0.f);
        a[k] = fmaxf((v - mu[k]) * rsqrtf(vr[k] + BN_EPS) * gm[k] + bt[k], 0.f);
    }
    // Wfc[128][2]: top rows f0..f0+7 -> p0/p1; bottom rows 64+f0.. -> p2/p3
    float wt[16], wb[16];
    #pragma unroll
    for (int k = 0; k < 4; ++k) {
        *(float4*)&wt[4 * k] = *(const float4*)&Wfc[2 * f0 + 4 * k];
        *(float4*)&wb[4 * k] = *(const float4*)&Wfc[128 + 2 * f0 + 4 * k];
    }
    float p0 = 0.f, p1 = 0.f, p2 = 0.f, p3 = 0.f;
    #pragma unroll
    for (int k = 0; k < 8; ++k) {
        p0 += a[k] * wt[2 * k];
        p1 += a[k] * wt[2 * k + 1];
        p2 += a[k] * wb[2 * k];
        p3 += a[k] * wb[2 * k + 1];
    }
    #pragma unroll
    for (int off = 4; off > 0; off >>= 1) {              // reduce within octet
        p0 += __shfl_xor(p0, off, 64);
        p1 += __shfl_xor(p1, off, 64);
        p2 += __shfl_xor(p2, off, 64);
        p3 += __shfl_xor(p3, off, 64);
    }
    if (ol == 0) uv[n] = make_float4(p0, p1, p2, p3);
}

// --- 5. edge head: 2 edges/thread; out = uv[row].xy + uv[col].zw + bfc ---
__global__ __launch_bounds__(256) void edgeout_kernel(const int* __restrict__ row,
                                                      const int* __restrict__ col,
                                                      const float4* __restrict__ uv,
                                                      const float* __restrict__ bfc,
                                                      float2* __restrict__ out) {
    int i = blockIdx.x * 256 + threadIdx.x;          // over N_EDGES/2 (grid exact)
    int e = i * 2;
    int2 rr = *(const int2*)&row[e];
    int2 cc = *(const int2*)&col[e];
    float4 a0 = uv[rr.x];
    float4 b0 = uv[cc.x];
    float4 a1 = uv[rr.y];
    float4 b1 = uv[cc.y];
    float c0 = bfc[0], c1 = bfc[1];
    float4 o = make_float4(a0.x + b0.z + c0, a0.y + b0.w + c1,
                           a1.x + b1.z + c0, a1.y + b1.w + c1);
    *(float4*)&out[e] = o;
}

extern "C" void kernel_launch(void* const* d_in, const int* in_sizes, int n_in,
                              void* d_out, int out_size, void* d_ws, size_t ws_size,
                              hipStream_t stream) {
    const float* x     = (const float*)d_in[0];
    const int*   ei    = (const int*)d_in[1];
    const int*   row   = ei;             // sources
    const int*   col   = ei + N_EDGES;   // targets
    const float* W1    = (const float*)d_in[2];
    const float* b1    = (const float*)d_in[3];
    const float* gamma = (const float*)d_in[4];
    const float* beta  = (const float*)d_in[5];
    const float* mean  = (const float*)d_in[6];
    const float* var   = (const float*)d_in[7];
    const float* Wfc   = (const float*)d_in[8];
    const float* bfc   = (const float*)d_in[9];
    float2* out = (float2*)d_out;

    char* ws = (char*)d_ws;
    size_t off = 0;
    ushort* h_s      = (ushort*)(ws + off); off += (size_t)N_NODES * D_HID * 2;    // 12.8 MB
    int*   binned    = (int*)(ws + off);    off += (size_t)N_BUCKETS * BCAP * 4;   // 12.8 MB
    int*   csr_src   = (int*)(ws + off);    off += (size_t)N_BUCKETS * BCAP * 4;   // 12.8 MB
    int*   bcursor   = (int*)(ws + off);    off += ((size_t)N_BUCKETS * 4 + 15) & ~(size_t)15;
    int2*  rs2       = (int2*)(ws + off);   off += (size_t)N_NODES * 8;            // 0.8 MB
    float* dinv      = (float*)(ws + off);  off += (size_t)N_NODES * 4;
    float4* uv       = (float4*)(ws + off); off += (size_t)N_NODES * 16;           // 1.6 MB

    hipMemsetAsync(bcursor, 0, N_BUCKETS * sizeof(int), stream);
    bin_scatter_kernel<<<N_BIN_BLOCKS, 1024, 0, stream>>>(row, col, bcursor, binned);
    bucket_csr_kernel<<<N_BUCKETS, 512, 0, stream>>>(binned, bcursor, csr_src, rs2, dinv);
    gemm_mfma_kernel<<<N_NODES / (16 * GT), 256, 0, stream>>>(x, W1, dinv, h_s);
    aggregate_kernel<<<N_NODES / 32, 256, 0, stream>>>(h_s, dinv, rs2, csr_src,
                                                       b1, gamma, beta, mean, var,
                                                       Wfc, uv);
    edgeout_kernel<<<N_EDGES / 512, 256, 0, stream>>>(row, col, uv, bfc, out);
}

// Round 7
// 190.499 us; speedup vs baseline: 4.7322x; 1.0390x over previous
//
#include <hip/hip_runtime.h>

#define N_NODES 100000
#define N_EDGES 1600000
#define D_IN 128
#define D_HID 64
#define BN_EPS 1e-5f

#define BUCKET_SHIFT 7
#define BUCKET_W 128                                    // nodes per bucket
#define N_BUCKETS ((N_NODES + BUCKET_W - 1) / BUCKET_W) // 782
#define BCAP 4096                                       // fixed per-bucket capacity (mean 2046, sigma 45)
#define N_BIN_BLOCKS 250
#define EDGES_PER_BLOCK (N_EDGES / N_BIN_BLOCKS)        // 6400 exact, 16B-aligned
#define E4_PER_BLOCK (EDGES_PER_BLOCK / 4)              // 1600 int4
#define GT 5                                            // gemm tiles per block (1250 blocks)

typedef __attribute__((ext_vector_type(8))) short bf16x8;
typedef __attribute__((ext_vector_type(4))) float f32x4;
typedef __attribute__((ext_vector_type(8))) _Float16 f16x8;

__device__ __forceinline__ ushort f2bf(float f) {       // RTNE fp32 -> bf16
    unsigned u = __float_as_uint(f);
    u += 0x7FFF + ((u >> 16) & 1);
    return (ushort)(u >> 16);
}

// --- 1. fused bin: LDS count -> reserve -> scatter; int4 edge reads ---
__global__ __launch_bounds__(1024) void bin_scatter_kernel(const int* __restrict__ row,
                                                           const int* __restrict__ col,
                                                           int* __restrict__ bcursor,
                                                           int* __restrict__ binned) {
    __shared__ int hist[N_BUCKETS];
    __shared__ int lbase[N_BUCKETS];
    const int t = threadIdx.x;
    for (int i = t; i < N_BUCKETS; i += 1024) hist[i] = 0;
    __syncthreads();
    const int e0 = blockIdx.x * EDGES_PER_BLOCK;
    const int4* __restrict__ colv = (const int4*)(col + e0);
    const int4* __restrict__ rowv = (const int4*)(row + e0);
    for (int j4 = t; j4 < E4_PER_BLOCK; j4 += 1024) {
        int4 c = colv[j4];
        atomicAdd(&hist[c.x >> BUCKET_SHIFT], 1);
        atomicAdd(&hist[c.y >> BUCKET_SHIFT], 1);
        atomicAdd(&hist[c.z >> BUCKET_SHIFT], 1);
        atomicAdd(&hist[c.w >> BUCKET_SHIFT], 1);
    }
    __syncthreads();
    for (int i = t; i < N_BUCKETS; i += 1024) {
        int h = hist[i];
        lbase[i] = h ? (i * BCAP + atomicAdd(&bcursor[i], h)) : 0;
        hist[i] = 0;   // local rank cursor
    }
    __syncthreads();
    for (int j4 = t; j4 < E4_PER_BLOCK; j4 += 1024) {    // col re-read is L2-hot
        int4 c = colv[j4];
        int4 r = rowv[j4];
        int cc[4] = {c.x, c.y, c.z, c.w};
        int rr[4] = {r.x, r.y, r.z, r.w};
        #pragma unroll
        for (int k = 0; k < 4; ++k) {
            int b = cc[k] >> BUCKET_SHIFT;
            int rank = atomicAdd(&hist[b], 1);
            binned[lbase[b] + rank] = ((cc[k] & (BUCKET_W - 1)) << 17) | rr[k];
        }
    }
}

// --- 2. bucket-local counting sort (fully LDS-staged) -> CSR + (start,cnt) + dinv ---
// binned read once (int4), sort scatter in LDS, coalesced int4 dump to global.
__global__ __launch_bounds__(512) void bucket_csr_kernel(const int* __restrict__ binned,
                                                         const int* __restrict__ bcursor,
                                                         int* __restrict__ csr_src,
                                                         int2* __restrict__ rs2,
                                                         float* __restrict__ dinv) {
    __shared__ int eb[BCAP];        // staged packed edges (16 KB)
    __shared__ int cl[BCAP];        // sorted local src ids (16 KB)
    __shared__ int hist[BUCKET_W];
    __shared__ int cursor[BUCKET_W];
    const int b = blockIdx.x;
    const int t = threadIdx.x;
    if (t < BUCKET_W) hist[t] = 0;
    __syncthreads();
    const int s = b * BCAP;
    const int cnt = bcursor[b];
    const int n4 = (cnt + 3) >> 2;
    const int4* __restrict__ binv = (const int4*)(binned + s);
    for (int i4 = t; i4 < n4; i4 += 512) {               // stage + histogram
        int4 v = binv[i4];
        int vv[4] = {v.x, v.y, v.z, v.w};
        #pragma unroll
        for (int k = 0; k < 4; ++k) {
            int idx = 4 * i4 + k;
            if (idx < cnt) {
                eb[idx] = vv[k];
                atomicAdd(&hist[vv[k] >> 17], 1);
            }
        }
    }
    __syncthreads();
    if (t < BUCKET_W) cursor[t] = hist[t];
    for (int off = 1; off < BUCKET_W; off <<= 1) {       // inclusive scan
        __syncthreads();
        int add = (t >= off && t < BUCKET_W) ? cursor[t - off] : 0;
        __syncthreads();
        if (t < BUCKET_W) cursor[t] += add;
    }
    __syncthreads();
    int excl = (t < BUCKET_W) ? (cursor[t] - hist[t]) : 0;
    __syncthreads();
    if (t < BUCKET_W) cursor[t] = excl;
    const int node = b * BUCKET_W + t;
    if (t < BUCKET_W && node < N_NODES) {
        rs2[node] = make_int2(s + excl, hist[t]);
        dinv[node] = rsqrtf(1.0f + (float)hist[t]);
    }
    __syncthreads();
    for (int i = t; i < cnt; i += 512) {                 // sort scatter in LDS
        int p = eb[i];
        int pos = atomicAdd(&cursor[p >> 17], 1);
        cl[pos] = p & 0x1FFFF;
    }
    __syncthreads();
    int4* __restrict__ csrv = (int4*)(csr_src + s);      // coalesced dump
    const int4* __restrict__ clv = (const int4*)cl;
    for (int i4 = t; i4 < n4; i4 += 512)
        csrv[i4] = clv[i4];
}

// --- 3. MFMA gemm: h_s(f16) = dinv[n] * (x @ W1) ---
__global__ __launch_bounds__(256) void gemm_mfma_kernel(const float* __restrict__ x,
                                                        const float* __restrict__ W,
                                                        const float* __restrict__ dinv,
                                                        ushort* __restrict__ h_s) {
    __shared__ ushort xb[16 * 136];
    const int t = threadIdx.x;
    const int l = t & 63;
    const int wv = t >> 6;
    const int q = l >> 4;       // quad
    const int m = l & 15;
    bf16x8 bf[4];               // B[k=32s+8q+j][n=16wv+m]
    {
        const int n = wv * 16 + m;
        #pragma unroll
        for (int s = 0; s < 4; ++s)
            #pragma unroll
            for (int j = 0; j < 8; ++j)
                bf[s][j] = (short)f2bf(W[(32 * s + 8 * q + j) * D_HID + n]);
    }
    for (int tile = 0; tile < GT; ++tile) {
        const int node0 = blockIdx.x * (16 * GT) + tile * 16;
        __syncthreads();
        for (int i = t; i < 512; i += 256) {             // 16 rows x 32 float4
            int r = i >> 5, c4 = i & 31;
            float4 v = *(const float4*)&x[(size_t)(node0 + r) * D_IN + c4 * 4];
            ushort4 u = make_ushort4(f2bf(v.x), f2bf(v.y), f2bf(v.z), f2bf(v.w));
            *(ushort4*)&xb[r * 136 + c4 * 4] = u;
        }
        __syncthreads();
        f32x4 acc = {0.f, 0.f, 0.f, 0.f};
        #pragma unroll
        for (int s = 0; s < 4; ++s) {
            bf16x8 af = *(const bf16x8*)&xb[m * 136 + 32 * s + 8 * q];
            acc = __builtin_amdgcn_mfma_f32_16x16x32_bf16(af, bf[s], acc, 0, 0, 0);
        }
        #pragma unroll
        for (int r = 0; r < 4; ++r) {
            int node = node0 + q * 4 + r;    // C/D: row=(lane>>4)*4+reg, col=lane&15
            _Float16 hv = (_Float16)(acc[r] * dinv[node]);
            h_s[node * D_HID + wv * 16 + m] = __builtin_bit_cast(unsigned short, hv);
        }
    }
}

// --- 4. fused aggregate + bias/BN/relu + fc projection ---
// 8 nodes per wave: one 8-lane octet per node, f16x8 (16B) per lane =
// one full 128B node line per gather group. (Verified R2 structure.)
__global__ __launch_bounds__(256) void aggregate_kernel(const ushort* __restrict__ h_s,
                                                        const float* __restrict__ dinv,
                                                        const int2* __restrict__ rs2,
                                                        const int* __restrict__ csr_src,
                                                        const float* __restrict__ b1,
                                                        const float* __restrict__ gamma,
                                                        const float* __restrict__ beta,
                                                        const float* __restrict__ mean,
                                                        const float* __restrict__ var,
                                                        const float* __restrict__ Wfc,
                                                        float4* __restrict__ uv) {
    const f16x8* __restrict__ hsv = (const f16x8*)h_s;   // [node][8] octets
    const int wvid = (blockIdx.x * 256 + threadIdx.x) >> 6; // wave id (grid exact)
    const int lane = threadIdx.x & 63;
    const int oct = lane >> 3;                           // node slot 0..7
    const int ol = lane & 7;                             // feature octet 0..7
    const int n = wvid * 8 + oct;                        // node
    f16x8 acc = hsv[n * 8 + ol];                         // self-loop (pre-scaled)
    const int2 rs = rs2[n];
    const int start = rs.x;
    const int cnt = rs.y;
    int j = 0;
    for (; j + 8 <= cnt; j += 8) {                       // 8 gathers in flight/octet
        int i0 = csr_src[start + j + 0];
        int i1 = csr_src[start + j + 1];
        int i2 = csr_src[start + j + 2];
        int i3 = csr_src[start + j + 3];
        int i4 = csr_src[start + j + 4];
        int i5 = csr_src[start + j + 5];
        int i6 = csr_src[start + j + 6];
        int i7 = csr_src[start + j + 7];
        f16x8 v0 = hsv[i0 * 8 + ol];
        f16x8 v1 = hsv[i1 * 8 + ol];
        f16x8 v2 = hsv[i2 * 8 + ol];
        f16x8 v3 = hsv[i3 * 8 + ol];
        f16x8 v4 = hsv[i4 * 8 + ol];
        f16x8 v5 = hsv[i5 * 8 + ol];
        f16x8 v6 = hsv[i6 * 8 + ol];
        f16x8 v7 = hsv[i7 * 8 + ol];
        acc += v0; acc += v1; acc += v2; acc += v3;
        acc += v4; acc += v5; acc += v6; acc += v7;
    }
    for (; j + 4 <= cnt; j += 4) {
        int i0 = csr_src[start + j + 0];
        int i1 = csr_src[start + j + 1];
        int i2 = csr_src[start + j + 2];
        int i3 = csr_src[start + j + 3];
        f16x8 v0 = hsv[i0 * 8 + ol];
        f16x8 v1 = hsv[i1 * 8 + ol];
        f16x8 v2 = hsv[i2 * 8 + ol];
        f16x8 v3 = hsv[i3 * 8 + ol];
        acc += v0; acc += v1; acc += v2; acc += v3;
    }
    for (; j + 2 <= cnt; j += 2) {
        int i0 = csr_src[start + j + 0];
        int i1 = csr_src[start + j + 1];
        f16x8 v0 = hsv[i0 * 8 + ol];
        f16x8 v1 = hsv[i1 * 8 + ol];
        acc += v0; acc += v1;
    }
    if (j < cnt)
        acc += hsv[csr_src[start + j] * 8 + ol];
    // epilogue: lane handles features f0..f0+7 of node n
    const float dn = dinv[n];
    const int f0 = 8 * ol;
    float a[8];
    #pragma unroll
    for (int k = 0; k < 8; ++k) a[k] = (float)acc[k] * dn;
    float bb[8], mu[8], vr[8], gm[8], bt[8];
    *(float4*)&bb[0] = *(const float4*)&b1[f0];    *(float4*)&bb[4] = *(const float4*)&b1[f0 + 4];
    *(float4*)&mu[0] = *(const float4*)&mean[f0];  *(float4*)&mu[4] = *(const float4*)&mean[f0 + 4];
    *(float4*)&vr[0] = *(const float4*)&var[f0];   *(float4*)&vr[4] = *(const float4*)&var[f0 + 4];
    *(float4*)&gm[0] = *(const float4*)&gamma[f0]; *(float4*)&gm[4] = *(const float4*)&gamma[f0 + 4];
    *(float4*)&bt[0] = *(const float4*)&beta[f0];  *(float4*)&bt[4] = *(const float4*)&beta[f0 + 4];
    #pragma unroll
    for (int k = 0; k < 8; ++k) {
        float v = fmaxf(a[k] + bb[k], 0.f);
        a[k] = fmaxf((v - mu[k]) * rsqrtf(vr[k] + BN_EPS) * gm[k] + bt[k], 0.f);
    }
    // Wfc[128][2]: top rows f0..f0+7 -> p0/p1; bottom rows 64+f0.. -> p2/p3
    float wt[16], wb[16];
    #pragma unroll
    for (int k = 0; k < 4; ++k) {
        *(float4*)&wt[4 * k] = *(const float4*)&Wfc[2 * f0 + 4 * k];
        *(float4*)&wb[4 * k] = *(const float4*)&Wfc[128 + 2 * f0 + 4 * k];
    }
    float p0 = 0.f, p1 = 0.f, p2 = 0.f, p3 = 0.f;
    #pragma unroll
    for (int k = 0; k < 8; ++k) {
        p0 += a[k] * wt[2 * k];
        p1 += a[k] * wt[2 * k + 1];
        p2 += a[k] * wb[2 * k];
        p3 += a[k] * wb[2 * k + 1];
    }
    #pragma unroll
    for (int off = 4; off > 0; off >>= 1) {              // reduce within octet
        p0 += __shfl_xor(p0, off, 64);
        p1 += __shfl_xor(p1, off, 64);
        p2 += __shfl_xor(p2, off, 64);
        p3 += __shfl_xor(p3, off, 64);
    }
    if (ol == 0) uv[n] = make_float4(p0, p1, p2, p3);
}

// --- 5. edge head: 2 edges/thread; out = uv[row].xy + uv[col].zw + bfc ---
__global__ __launch_bounds__(256) void edgeout_kernel(const int* __restrict__ row,
                                                      const int* __restrict__ col,
                                                      const float4* __restrict__ uv,
                                                      const float* __restrict__ bfc,
                                                      float2* __restrict__ out) {
    int i = blockIdx.x * 256 + threadIdx.x;          // over N_EDGES/2 (grid exact)
    int e = i * 2;
    int2 rr = *(const int2*)&row[e];
    int2 cc = *(const int2*)&col[e];
    float4 a0 = uv[rr.x];
    float4 b0 = uv[cc.x];
    float4 a1 = uv[rr.y];
    float4 b1 = uv[cc.y];
    float c0 = bfc[0], c1 = bfc[1];
    float4 o = make_float4(a0.x + b0.z + c0, a0.y + b0.w + c1,
                           a1.x + b1.z + c0, a1.y + b1.w + c1);
    *(float4*)&out[e] = o;
}

extern "C" void kernel_launch(void* const* d_in, const int* in_sizes, int n_in,
                              void* d_out, int out_size, void* d_ws, size_t ws_size,
                              hipStream_t stream) {
    const float* x     = (const float*)d_in[0];
    const int*   ei    = (const int*)d_in[1];
    const int*   row   = ei;             // sources
    const int*   col   = ei + N_EDGES;   // targets
    const float* W1    = (const float*)d_in[2];
    const float* b1    = (const float*)d_in[3];
    const float* gamma = (const float*)d_in[4];
    const float* beta  = (const float*)d_in[5];
    const float* mean  = (const float*)d_in[6];
    const float* var   = (const float*)d_in[7];
    const float* Wfc   = (const float*)d_in[8];
    const float* bfc   = (const float*)d_in[9];
    float2* out = (float2*)d_out;

    char* ws = (char*)d_ws;
    size_t off = 0;
    ushort* h_s      = (ushort*)(ws + off); off += (size_t)N_NODES * D_HID * 2;    // 12.8 MB
    int*   binned    = (int*)(ws + off);    off += (size_t)N_BUCKETS * BCAP * 4;   // 12.8 MB
    int*   csr_src   = (int*)(ws + off);    off += (size_t)N_BUCKETS * BCAP * 4;   // 12.8 MB
    int*   bcursor   = (int*)(ws + off);    off += ((size_t)N_BUCKETS * 4 + 15) & ~(size_t)15;
    int2*  rs2       = (int2*)(ws + off);   off += (size_t)N_NODES * 8;            // 0.8 MB
    float* dinv      = (float*)(ws + off);  off += (size_t)N_NODES * 4;
    float4* uv       = (float4*)(ws + off); off += (size_t)N_NODES * 16;           // 1.6 MB

    hipMemsetAsync(bcursor, 0, N_BUCKETS * sizeof(int), stream);
    bin_scatter_kernel<<<N_BIN_BLOCKS, 1024, 0, stream>>>(row, col, bcursor, binned);
    bucket_csr_kernel<<<N_BUCKETS, 512, 0, stream>>>(binned, bcursor, csr_src, rs2, dinv);
    gemm_mfma_kernel<<<N_NODES / (16 * GT), 256, 0, stream>>>(x, W1, dinv, h_s);
    aggregate_kernel<<<N_NODES / 32, 256, 0, stream>>>(h_s, dinv, rs2, csr_src,
                                                       b1, gamma, beta, mean, var,
                                                       Wfc, uv);
    edgeout_kernel<<<N_EDGES / 512, 256, 0, stream>>>(row, col, uv, bfc, out);
}